// Round 4
// baseline (331.789 us; speedup 1.0000x reference)
//
#include <hip/hip_runtime.h>
#include <math.h>

#define NG    64
#define NPG   2048
#define NTOT  (NG*NPG)     // 131072
#define ZD    64
#define PD    128
#define MH    256

typedef __attribute__((ext_vector_type(8))) short bf16x8;
typedef __attribute__((ext_vector_type(4))) float f32x4;

// ---------- helpers ----------
__device__ __forceinline__ unsigned short f2bf(float f){
  unsigned u = __float_as_uint(f);
  unsigned r = u + 0x7FFFu + ((u >> 16) & 1u);
  return (unsigned short)(r >> 16);
}
__device__ __forceinline__ float bf2f(unsigned short s){
  return __uint_as_float(((unsigned)s) << 16);
}
__device__ __forceinline__ float gelu_f(float x){
  float t = 0.7978845608028654f * fmaf(0.044715f * x, x * x, x);
  float e = __expf(2.0f * t);
  float th = 1.0f - 2.0f / (e + 1.0f);   // robust at e->inf
  return 0.5f * x * (1.0f + th);
}

// ---------- K1: fused zstat (blocks 0..63) + pool (blocks 64..1087) ----------
__launch_bounds__(256)
__global__ void k1_pool_zstat(const float* __restrict__ x, const float* __restrict__ z,
                              float* __restrict__ pooled, float* __restrict__ St,
                              float* __restrict__ C){
  __shared__ __align__(16) unsigned short s_zt[64 * 264];  // 33792 B
  __shared__ float s_cred[4096];                           // 16 KB (pool reuses first 256)
  __shared__ float s_st[4][64];
  int tid = threadIdx.x;

  if (blockIdx.x >= 64){
    // ---- pool: adaptive pool x [131072,256] -> pooled [64,128] ----
    int bi = blockIdx.x - 64;
    int b  = bi >> 4;
    int oh = bi & 15;
    int c4 = tid & 63;
    int rq = tid >> 6;
    const float4* x4 = (const float4*)x;
    size_t base = (size_t)(b * NPG + oh * 128) * 64;
    float4 acc = make_float4(0.f, 0.f, 0.f, 0.f);
    #pragma unroll 8
    for (int i = 0; i < 32; i++){
      float4 v = x4[base + (size_t)(rq + i * 4) * 64 + c4];
      acc.x += v.x; acc.y += v.y; acc.z += v.z; acc.w += v.w;
    }
    s_cred[tid] = acc.x + acc.y + acc.z + acc.w;
    __syncthreads();
    if (tid < 8){
      float s = 0.f;
      #pragma unroll
      for (int w = 0; w < 4; w++)
        #pragma unroll
        for (int j = 0; j < 8; j++)
          s += s_cred[w * 64 + tid * 8 + j];
      pooled[b * PD + oh * 8 + tid] = s * (1.0f / 4096.0f);
    }
    return;
  }

  // ---- zstat: one block per graph, 2048 rows in 8 chunks of 256 ----
  int g = blockIdx.x;
  int lane = tid & 63, wave = tid >> 6;
  int col = lane & 15, quad = lane >> 4;
  const float4* z4 = (const float4*)z + (size_t)g * 2048 * 16;
  int d4 = tid & 15;

  f32x4 acc[4][4];
  #pragma unroll
  for (int a = 0; a < 4; a++)
    #pragma unroll
    for (int b = 0; b < 4; b++) acc[a][b] = (f32x4)(0.f);
  float s0 = 0.f, s1 = 0.f, s2 = 0.f, s3 = 0.f;

  for (int ch = 0; ch < 8; ch++){
    #pragma unroll
    for (int i = 0; i < 16; i++){
      int idx = tid + i * 256;       // 4096 = 256 rows x 16 f4cols
      int m = idx >> 4;
      float4 v = z4[ch * 4096 + idx];
      s0 += v.x; s1 += v.y; s2 += v.z; s3 += v.w;
      s_zt[(d4 * 4 + 0) * 264 + m] = f2bf(v.x);
      s_zt[(d4 * 4 + 1) * 264 + m] = f2bf(v.y);
      s_zt[(d4 * 4 + 2) * 264 + m] = f2bf(v.z);
      s_zt[(d4 * 4 + 3) * 264 + m] = f2bf(v.w);
    }
    __syncthreads();
    #pragma unroll
    for (int ks = 0; ks < 2; ks++){
      int k0 = wave * 64 + ks * 32;
      bf16x8 fr[4];
      #pragma unroll
      for (int t = 0; t < 4; t++)
        fr[t] = *(const bf16x8*)&s_zt[(t * 16 + col) * 264 + k0 + quad * 8];
      #pragma unroll
      for (int mt = 0; mt < 4; mt++)
        #pragma unroll
        for (int nt = 0; nt < 4; nt++)
          acc[mt][nt] = __builtin_amdgcn_mfma_f32_16x16x32_bf16(fr[mt], fr[nt], acc[mt][nt], 0, 0, 0);
    }
    __syncthreads();
  }

  // per-graph sums: reduce rowphase within wave (xor 16/32), then across waves via LDS
  s0 += __shfl_xor(s0, 16); s0 += __shfl_xor(s0, 32);
  s1 += __shfl_xor(s1, 16); s1 += __shfl_xor(s1, 32);
  s2 += __shfl_xor(s2, 16); s2 += __shfl_xor(s2, 32);
  s3 += __shfl_xor(s3, 16); s3 += __shfl_xor(s3, 32);
  if (quad == 0)
    *(float4*)&s_st[wave][d4 * 4] = make_float4(s0, s1, s2, s3);
  __syncthreads();
  if (tid < 64)
    St[tid * 64 + g] = s_st[0][tid] + s_st[1][tid] + s_st[2][tid] + s_st[3][tid];

  // C block-reduce: sequential wave accumulate into s_cred, then atomicAdd to C
  #pragma unroll
  for (int w = 0; w < 4; w++){
    if (wave == w){
      #pragma unroll
      for (int mt = 0; mt < 4; mt++)
        #pragma unroll
        for (int nt = 0; nt < 4; nt++)
          #pragma unroll
          for (int r = 0; r < 4; r++){
            int p = mt * 16 + quad * 4 + r;
            int qc = nt * 16 + col;
            if (w == 0) s_cred[p * 64 + qc]  = acc[mt][nt][r];
            else        s_cred[p * 64 + qc] += acc[mt][nt][r];
          }
    }
    __syncthreads();
  }
  for (int f = tid; f < 4096; f += 256)
    atomicAdd(&C[f], s_cred[f]);
}

// ---------- K2: fused Wbf precompute + gmat (G in regs) + analytic BN stats ----------
__launch_bounds__(256)
__global__ void k2_stats(const float* __restrict__ pooled, const float* __restrict__ W1,
                         const float* __restrict__ b1, const float* __restrict__ gamma,
                         const float* __restrict__ beta, const float* __restrict__ C,
                         const float* __restrict__ St, float* __restrict__ Aj,
                         float* __restrict__ cprime, unsigned short* __restrict__ Wbf){
  __shared__ float pl[64 * 129];   // padded: stride 129 -> 2-way alias only
  int tid = threadIdx.x;
  int jc = tid >> 6, lane = tid & 63;
  int j = blockIdx.x * 4 + jc;

  // emit W1_top as bf16 [j][k]
  Wbf[(size_t)j * 64 + lane] = f2bf(W1[(size_t)lane * 256 + j]);

  // stage pooled
  for (int idx = tid; idx < 8192; idx += 256)
    pl[(idx >> 7) * 129 + (idx & 127)] = pooled[idx];
  __syncthreads();

  // gmat: thread (lane=b) computes G[b][j], kept in register
  float g = b1[j];
  #pragma unroll 8
  for (int k = 0; k < 128; k++)
    g = fmaf(pl[lane * 129 + k], W1[(size_t)(ZD + k) * MH + j], g);

  // stats
  float wl = W1[(size_t)lane * MH + j];    // W1_top[lane][j]
  float t1 = 0.f, t2 = 0.f;
  #pragma unroll
  for (int q = 0; q < 64; q++){
    float wq = __uint_as_float(__builtin_amdgcn_readlane(__float_as_uint(wl), q));
    t1 = fmaf(C [q * 64 + lane], wq, t1);  // (C w)_p, C symmetric
    t2 = fmaf(St[q * 64 + lane], wq, t2);  // S_p . w
  }
  float v_wcw = wl * t1;
  float v_gs  = g * t2;
  float v_s   = t2;
  float v_g   = g;
  float v_g2  = g * g;
  #pragma unroll
  for (int off = 32; off; off >>= 1){
    v_wcw += __shfl_xor(v_wcw, off);
    v_gs  += __shfl_xor(v_gs , off);
    v_s   += __shfl_xor(v_s  , off);
    v_g   += __shfl_xor(v_g  , off);
    v_g2  += __shfl_xor(v_g2 , off);
  }
  const float invN = 1.0f / (float)NTOT;
  float mean = v_s * invN + v_g * (1.0f / 64.0f);
  float eh2  = v_wcw * invN + 2.0f * invN * v_gs + v_g2 * (1.0f / 64.0f);
  float var  = eh2 - mean * mean;
  float aj = gamma[j] * rsqrtf(var + 1e-5f);
  if (lane == 0) Aj[j] = aj;
  cprime[lane * MH + j] = fmaf(aj, g, beta[j] - aj * mean);
}

// ---------- K3: MFMA fused  u=z@W1_top -> BN affine -> GELU -> @W2 + b2 ----------
// 128 nodes x 256 j per block. A-fragments loaded DIRECTLY from global z
// (A[m=lane&15][k=quad*8+j] -> 32B-contiguous row chunks), hi/lo bf16 split in regs.
// B-fragments from precomputed global Wbf (L2-resident). No LDS staging.
__launch_bounds__(256, 2)
__global__ void final_kernel(const float* __restrict__ z, const unsigned short* __restrict__ Wbf,
                             const float* __restrict__ Aj, const float* __restrict__ cp,
                             const float* __restrict__ W2, const float* __restrict__ b2,
                             float* __restrict__ out){
  __shared__ float slab[2][384];
  int tid = threadIdx.x;
  int n0 = blockIdx.x * 128;
  int g = blockIdx.x >> 4;

  int lane = tid & 63, wave = tid >> 6;
  int wm = wave & 1, wn = wave >> 1;
  int col = lane & 15, quad = lane >> 4;
  int mbase = wm * 64, nbase = wn * 128;

  f32x4 acc[4][8];
  #pragma unroll
  for (int mt = 0; mt < 4; mt++)
    #pragma unroll
    for (int nt = 0; nt < 8; nt++) acc[mt][nt] = (f32x4)(0.f);

  #pragma unroll
  for (int kh = 0; kh < 2; kh++){
    // load+convert A fragments: rows mbase+mt*16+col, k = kh*32 + quad*8 .. +7
    bf16x8 ah[4], al[4];
    #pragma unroll
    for (int mt = 0; mt < 4; mt++){
      const float4* zr = (const float4*)(z + (size_t)(n0 + mbase + mt * 16 + col) * 64
                                           + kh * 32 + quad * 8);
      float4 v0 = zr[0], v1 = zr[1];
      float f[8] = {v0.x, v0.y, v0.z, v0.w, v1.x, v1.y, v1.z, v1.w};
      #pragma unroll
      for (int e = 0; e < 8; e++){
        unsigned short h = f2bf(f[e]);
        ah[mt][e] = (short)h;
        al[mt][e] = (short)f2bf(f[e] - bf2f(h));
      }
    }
    // B fragments for this k-half
    bf16x8 bv[8];
    #pragma unroll
    for (int nt = 0; nt < 8; nt++)
      bv[nt] = *(const bf16x8*)&Wbf[(size_t)(nbase + nt * 16 + col) * 64 + kh * 32 + quad * 8];
    // hi then lo MFMAs (bv reused)
    #pragma unroll
    for (int nt = 0; nt < 8; nt++)
      #pragma unroll
      for (int mt = 0; mt < 4; mt++)
        acc[mt][nt] = __builtin_amdgcn_mfma_f32_16x16x32_bf16(ah[mt], bv[nt], acc[mt][nt], 0, 0, 0);
    #pragma unroll
    for (int nt = 0; nt < 8; nt++)
      #pragma unroll
      for (int mt = 0; mt < 4; mt++)
        acc[mt][nt] = __builtin_amdgcn_mfma_f32_16x16x32_bf16(al[mt], bv[nt], acc[mt][nt], 0, 0, 0);
  }

  // per-lane j constants
  float aj[8], cj[8], w2a[8], w2b[8], w2c[8];
  #pragma unroll
  for (int nt = 0; nt < 8; nt++){
    int j = nbase + nt * 16 + col;
    aj[nt] = Aj[j];
    cj[nt] = cp[g * MH + j];
    w2a[nt] = W2[j * 3 + 0];
    w2b[nt] = W2[j * 3 + 1];
    w2c[nt] = W2[j * 3 + 2];
  }

  // epilogue: BN affine -> GELU -> dot W2, reduce over j
  #pragma unroll
  for (int mt = 0; mt < 4; mt++){
    #pragma unroll
    for (int r = 0; r < 4; r++){
      float o0 = 0.f, o1 = 0.f, o2 = 0.f;
      #pragma unroll
      for (int nt = 0; nt < 8; nt++){
        float h  = fmaf(aj[nt], acc[mt][nt][r], cj[nt]);
        float ge = gelu_f(h);
        o0 = fmaf(ge, w2a[nt], o0);
        o1 = fmaf(ge, w2b[nt], o1);
        o2 = fmaf(ge, w2c[nt], o2);
      }
      #pragma unroll
      for (int off = 8; off; off >>= 1){
        o0 += __shfl_xor(o0, off);
        o1 += __shfl_xor(o1, off);
        o2 += __shfl_xor(o2, off);
      }
      if (col == 0){
        int node = mbase + mt * 16 + quad * 4 + r;
        slab[wn][node * 3 + 0] = o0;
        slab[wn][node * 3 + 1] = o1;
        slab[wn][node * 3 + 2] = o2;
      }
    }
  }
  __syncthreads();
  float b2v[3] = {b2[0], b2[1], b2[2]};
  for (int f = tid; f < 384; f += 256)
    out[(size_t)blockIdx.x * 384 + f] = slab[0][f] + slab[1][f] + b2v[f % 3];
}

// ---------- launch ----------
extern "C" void kernel_launch(void* const* d_in, const int* in_sizes, int n_in,
                              void* d_out, int out_size, void* d_ws, size_t ws_size,
                              hipStream_t stream){
  (void)in_sizes; (void)n_in; (void)out_size; (void)ws_size;
  const float* x     = (const float*)d_in[0];
  const float* z     = (const float*)d_in[2];
  const float* W1    = (const float*)d_in[3];
  const float* b1    = (const float*)d_in[4];
  const float* gamma = (const float*)d_in[5];
  const float* beta  = (const float*)d_in[6];
  const float* W2    = (const float*)d_in[7];
  const float* b2    = (const float*)d_in[8];
  float* out = (float*)d_out;

  float* W = (float*)d_ws;
  float* pooled = W;                         // 0     .. 8191
  float* St     = W + 8192;                  // 8192  .. 12287
  float* C      = W + 12288;                 // 12288 .. 16383
  float* Aj     = W + 16384;                 // 16384 .. 16639
  float* CP     = W + 16640;                 // 16640 .. 33023
  unsigned short* Wbf = (unsigned short*)(W + 33024);  // 16384 ushorts

  // zero C only (St is single-writer now)
  hipMemsetAsync((char*)d_ws + 12288 * 4, 0, 4096 * 4, stream);

  k1_pool_zstat<<<dim3(1088), dim3(256), 0, stream>>>(x, z, pooled, St, C);
  k2_stats     <<<dim3(64),   dim3(256), 0, stream>>>(pooled, W1, b1, gamma, beta, C, St, Aj, CP, Wbf);
  final_kernel <<<dim3(NTOT / 128), dim3(256), 0, stream>>>(z, Wbf, Aj, CP, W2, b2, out);
}

// Round 5
// 284.687 us; speedup vs baseline: 1.1655x; 1.1655x over previous
//
#include <hip/hip_runtime.h>
#include <math.h>

#define NG    64
#define NPG   2048
#define NTOT  (NG*NPG)     // 131072
#define ZD    64
#define PD    128
#define MH    256

typedef __attribute__((ext_vector_type(8))) short bf16x8;
typedef __attribute__((ext_vector_type(4))) float f32x4;

// ---------- helpers ----------
__device__ __forceinline__ unsigned short f2bf(float f){
  unsigned u = __float_as_uint(f);
  unsigned r = u + 0x7FFFu + ((u >> 16) & 1u);
  return (unsigned short)(r >> 16);
}
__device__ __forceinline__ float bf2f(unsigned short s){
  return __uint_as_float(((unsigned)s) << 16);
}
__device__ __forceinline__ float gelu_f(float x){
  float t = 0.7978845608028654f * fmaf(0.044715f * x, x * x, x);
  float e = __expf(2.0f * t);
  float th = 1.0f - 2.0f / (e + 1.0f);   // robust at e->inf
  return 0.5f * x * (1.0f + th);
}

// ---------- K1: fused zstat (blocks 0..255) + pool (blocks 256..1279) ----------
// zstat: 4 blocks/graph, 512 rows each (parallelism > atomics: 64-block variant
// regressed to 114 us on the long-tail, round 4). St written as per-q4 partials.
__launch_bounds__(256)
__global__ void k1_pool_zstat(const float* __restrict__ x, const float* __restrict__ z,
                              float* __restrict__ pooled, float* __restrict__ Stp,
                              float* __restrict__ C){
  __shared__ __align__(16) unsigned short s_zt[64 * 264];  // 33792 B
  __shared__ float s_cred[4096];                           // 16 KB (pool reuses first 256)
  __shared__ float s_st[4][64];
  int tid = threadIdx.x;

  if (blockIdx.x >= 256){
    // ---- pool: adaptive pool x [131072,256] -> pooled [64,128] ----
    int bi = blockIdx.x - 256;
    int b  = bi >> 4;
    int oh = bi & 15;
    int c4 = tid & 63;
    int rq = tid >> 6;
    const float4* x4 = (const float4*)x;
    size_t base = (size_t)(b * NPG + oh * 128) * 64;
    float4 acc = make_float4(0.f, 0.f, 0.f, 0.f);
    #pragma unroll 8
    for (int i = 0; i < 32; i++){
      float4 v = x4[base + (size_t)(rq + i * 4) * 64 + c4];
      acc.x += v.x; acc.y += v.y; acc.z += v.z; acc.w += v.w;
    }
    s_cred[tid] = acc.x + acc.y + acc.z + acc.w;
    __syncthreads();
    if (tid < 8){
      float s = 0.f;
      #pragma unroll
      for (int w = 0; w < 4; w++)
        #pragma unroll
        for (int j = 0; j < 8; j++)
          s += s_cred[w * 64 + tid * 8 + j];
      pooled[b * PD + oh * 8 + tid] = s * (1.0f / 4096.0f);
    }
    return;
  }

  // ---- zstat ----
  int blk = blockIdx.x;           // 0..255
  int g = blk >> 2, q4 = blk & 3;
  int lane = tid & 63, wave = tid >> 6;
  int col = lane & 15, quad = lane >> 4;
  const float4* z4 = (const float4*)z + ((size_t)g * 2048 + q4 * 512) * 16;
  int d4 = tid & 15;

  f32x4 acc[4][4];
  #pragma unroll
  for (int a = 0; a < 4; a++)
    #pragma unroll
    for (int b = 0; b < 4; b++) acc[a][b] = (f32x4)(0.f);
  float s0 = 0.f, s1 = 0.f, s2 = 0.f, s3 = 0.f;

  for (int ch = 0; ch < 2; ch++){
    #pragma unroll
    for (int i = 0; i < 16; i++){
      int idx = tid + i * 256;       // 4096 = 256 rows x 16 f4cols
      int m = idx >> 4;
      float4 v = z4[ch * 4096 + idx];
      s0 += v.x; s1 += v.y; s2 += v.z; s3 += v.w;
      s_zt[(d4 * 4 + 0) * 264 + m] = f2bf(v.x);
      s_zt[(d4 * 4 + 1) * 264 + m] = f2bf(v.y);
      s_zt[(d4 * 4 + 2) * 264 + m] = f2bf(v.z);
      s_zt[(d4 * 4 + 3) * 264 + m] = f2bf(v.w);
    }
    __syncthreads();
    #pragma unroll
    for (int ks = 0; ks < 2; ks++){
      int k0 = wave * 64 + ks * 32;
      bf16x8 fr[4];
      #pragma unroll
      for (int t = 0; t < 4; t++)
        fr[t] = *(const bf16x8*)&s_zt[(t * 16 + col) * 264 + k0 + quad * 8];
      #pragma unroll
      for (int mt = 0; mt < 4; mt++)
        #pragma unroll
        for (int nt = 0; nt < 4; nt++)
          acc[mt][nt] = __builtin_amdgcn_mfma_f32_16x16x32_bf16(fr[mt], fr[nt], acc[mt][nt], 0, 0, 0);
    }
    __syncthreads();
  }

  // per-graph sums: reduce rowphase within wave (xor 16/32), cross-wave via LDS,
  // then single-writer store into partial slot q4 (no atomics, no memset)
  s0 += __shfl_xor(s0, 16); s0 += __shfl_xor(s0, 32);
  s1 += __shfl_xor(s1, 16); s1 += __shfl_xor(s1, 32);
  s2 += __shfl_xor(s2, 16); s2 += __shfl_xor(s2, 32);
  s3 += __shfl_xor(s3, 16); s3 += __shfl_xor(s3, 32);
  if (quad == 0)
    *(float4*)&s_st[wave][d4 * 4] = make_float4(s0, s1, s2, s3);
  __syncthreads();
  if (tid < 64)
    Stp[q4 * 4096 + tid * 64 + g] = s_st[0][tid] + s_st[1][tid] + s_st[2][tid] + s_st[3][tid];

  // C block-reduce: sequential wave accumulate into s_cred, then atomicAdd to C
  #pragma unroll
  for (int w = 0; w < 4; w++){
    if (wave == w){
      #pragma unroll
      for (int mt = 0; mt < 4; mt++)
        #pragma unroll
        for (int nt = 0; nt < 4; nt++)
          #pragma unroll
          for (int r = 0; r < 4; r++){
            int p = mt * 16 + quad * 4 + r;
            int qc = nt * 16 + col;
            if (w == 0) s_cred[p * 64 + qc]  = acc[mt][nt][r];
            else        s_cred[p * 64 + qc] += acc[mt][nt][r];
          }
    }
    __syncthreads();
  }
  for (int f = tid; f < 4096; f += 256)
    atomicAdd(&C[f], s_cred[f]);
}

// ---------- K2: fused Wbf precompute + gmat (G in regs) + analytic BN stats ----------
__launch_bounds__(256)
__global__ void k2_stats(const float* __restrict__ pooled, const float* __restrict__ W1,
                         const float* __restrict__ b1, const float* __restrict__ gamma,
                         const float* __restrict__ beta, const float* __restrict__ C,
                         const float* __restrict__ Stp, float* __restrict__ Aj,
                         float* __restrict__ cprime, unsigned short* __restrict__ Wbf){
  __shared__ float pl[64 * 129];   // padded: stride 129 -> 2-way alias only
  __shared__ float sts[4096];      // St reduced from 4 partials
  int tid = threadIdx.x;
  int jc = tid >> 6, lane = tid & 63;
  int j = blockIdx.x * 4 + jc;

  // emit W1_top as bf16 [j][k]
  Wbf[(size_t)j * 64 + lane] = f2bf(W1[(size_t)lane * 256 + j]);

  // stage pooled + reduce St partials
  for (int idx = tid; idx < 8192; idx += 256)
    pl[(idx >> 7) * 129 + (idx & 127)] = pooled[idx];
  for (int idx = tid; idx < 4096; idx += 256)
    sts[idx] = Stp[idx] + Stp[4096 + idx] + Stp[8192 + idx] + Stp[12288 + idx];
  __syncthreads();

  // gmat: thread (lane=b) computes G[b][j], kept in register
  float g = b1[j];
  #pragma unroll 8
  for (int k = 0; k < 128; k++)
    g = fmaf(pl[lane * 129 + k], W1[(size_t)(ZD + k) * MH + j], g);

  // stats
  float wl = W1[(size_t)lane * MH + j];    // W1_top[lane][j]
  float t1 = 0.f, t2 = 0.f;
  #pragma unroll
  for (int q = 0; q < 64; q++){
    float wq = __uint_as_float(__builtin_amdgcn_readlane(__float_as_uint(wl), q));
    t1 = fmaf(C  [q * 64 + lane], wq, t1);  // (C w)_p, C symmetric
    t2 = fmaf(sts[q * 64 + lane], wq, t2);  // S_p . w
  }
  float v_wcw = wl * t1;
  float v_gs  = g * t2;
  float v_s   = t2;
  float v_g   = g;
  float v_g2  = g * g;
  #pragma unroll
  for (int off = 32; off; off >>= 1){
    v_wcw += __shfl_xor(v_wcw, off);
    v_gs  += __shfl_xor(v_gs , off);
    v_s   += __shfl_xor(v_s  , off);
    v_g   += __shfl_xor(v_g  , off);
    v_g2  += __shfl_xor(v_g2 , off);
  }
  const float invN = 1.0f / (float)NTOT;
  float mean = v_s * invN + v_g * (1.0f / 64.0f);
  float eh2  = v_wcw * invN + 2.0f * invN * v_gs + v_g2 * (1.0f / 64.0f);
  float var  = eh2 - mean * mean;
  float aj = gamma[j] * rsqrtf(var + 1e-5f);
  if (lane == 0) Aj[j] = aj;
  cprime[lane * MH + j] = fmaf(aj, g, beta[j] - aj * mean);
}

// ---------- K3: MFMA fused  u=z@W1_top -> BN affine -> GELU -> @W2 + b2 ----------
// 128 nodes x 256 j per block; z split hi/lo bf16 (K=128) staged in LDS;
// B-fragments direct from precomputed global Wbf (L2-resident). (Round-3 best.)
__launch_bounds__(256, 2)
__global__ void final_kernel(const float* __restrict__ z, const unsigned short* __restrict__ Wbf,
                             const float* __restrict__ Aj, const float* __restrict__ cp,
                             const float* __restrict__ W2, const float* __restrict__ b2,
                             float* __restrict__ out){
  __shared__ __align__(16) unsigned short zt[128 * 136];  // [m][k0..127 = hi|lo], pad 8
  __shared__ float slab[2][384];
  int tid = threadIdx.x;
  int n0 = blockIdx.x * 128;
  int g = blockIdx.x >> 4;

  // stage z tile hi/lo
  const float4* z4 = (const float4*)z + (size_t)n0 * 16;
  #pragma unroll
  for (int i = 0; i < 8; i++){
    int idx = tid + i * 256;           // 2048 = 128 m x 16 d4
    int m = idx >> 4, d4 = idx & 15;
    float4 v = z4[idx];
    ushort4 h, l;
    h.x = f2bf(v.x); l.x = f2bf(v.x - bf2f(h.x));
    h.y = f2bf(v.y); l.y = f2bf(v.y - bf2f(h.y));
    h.z = f2bf(v.z); l.z = f2bf(v.z - bf2f(h.z));
    h.w = f2bf(v.w); l.w = f2bf(v.w - bf2f(h.w));
    *(ushort4*)&zt[m * 136 + d4 * 4]      = h;
    *(ushort4*)&zt[m * 136 + 64 + d4 * 4] = l;
  }
  __syncthreads();

  int lane = tid & 63, wave = tid >> 6;
  int wm = wave & 1, wn = wave >> 1;
  int col = lane & 15, quad = lane >> 4;
  int mbase = wm * 64, nbase = wn * 128;

  f32x4 acc[4][8];
  #pragma unroll
  for (int mt = 0; mt < 4; mt++)
    #pragma unroll
    for (int nt = 0; nt < 8; nt++) acc[mt][nt] = (f32x4)(0.f);

  #pragma unroll
  for (int ks = 0; ks < 4; ks++){
    int k0 = ks * 32;                  // A: k over 0..127 (hi|lo); B: (ks&1)*32
    bf16x8 af[4];
    #pragma unroll
    for (int mt = 0; mt < 4; mt++)
      af[mt] = *(const bf16x8*)&zt[(mbase + mt * 16 + col) * 136 + k0 + quad * 8];
    #pragma unroll
    for (int nt = 0; nt < 8; nt++){
      bf16x8 bv = *(const bf16x8*)&Wbf[(size_t)(nbase + nt * 16 + col) * 64 + (ks & 1) * 32 + quad * 8];
      #pragma unroll
      for (int mt = 0; mt < 4; mt++)
        acc[mt][nt] = __builtin_amdgcn_mfma_f32_16x16x32_bf16(af[mt], bv, acc[mt][nt], 0, 0, 0);
    }
  }

  // per-lane j constants
  float aj[8], cj[8], w2a[8], w2b[8], w2c[8];
  #pragma unroll
  for (int nt = 0; nt < 8; nt++){
    int j = nbase + nt * 16 + col;
    aj[nt] = Aj[j];
    cj[nt] = cp[g * MH + j];
    w2a[nt] = W2[j * 3 + 0];
    w2b[nt] = W2[j * 3 + 1];
    w2c[nt] = W2[j * 3 + 2];
  }

  // epilogue: BN affine -> GELU -> dot W2, reduce over j
  #pragma unroll
  for (int mt = 0; mt < 4; mt++){
    #pragma unroll
    for (int r = 0; r < 4; r++){
      float o0 = 0.f, o1 = 0.f, o2 = 0.f;
      #pragma unroll
      for (int nt = 0; nt < 8; nt++){
        float h  = fmaf(aj[nt], acc[mt][nt][r], cj[nt]);
        float ge = gelu_f(h);
        o0 = fmaf(ge, w2a[nt], o0);
        o1 = fmaf(ge, w2b[nt], o1);
        o2 = fmaf(ge, w2c[nt], o2);
      }
      #pragma unroll
      for (int off = 8; off; off >>= 1){
        o0 += __shfl_xor(o0, off);
        o1 += __shfl_xor(o1, off);
        o2 += __shfl_xor(o2, off);
      }
      if (col == 0){
        int node = mbase + mt * 16 + quad * 4 + r;
        slab[wn][node * 3 + 0] = o0;
        slab[wn][node * 3 + 1] = o1;
        slab[wn][node * 3 + 2] = o2;
      }
    }
  }
  __syncthreads();
  float b2v[3] = {b2[0], b2[1], b2[2]};
  for (int f = tid; f < 384; f += 256)
    out[(size_t)blockIdx.x * 384 + f] = slab[0][f] + slab[1][f] + b2v[f % 3];
}

// ---------- launch ----------
extern "C" void kernel_launch(void* const* d_in, const int* in_sizes, int n_in,
                              void* d_out, int out_size, void* d_ws, size_t ws_size,
                              hipStream_t stream){
  (void)in_sizes; (void)n_in; (void)out_size; (void)ws_size;
  const float* x     = (const float*)d_in[0];
  const float* z     = (const float*)d_in[2];
  const float* W1    = (const float*)d_in[3];
  const float* b1    = (const float*)d_in[4];
  const float* gamma = (const float*)d_in[5];
  const float* beta  = (const float*)d_in[6];
  const float* W2    = (const float*)d_in[7];
  const float* b2    = (const float*)d_in[8];
  float* out = (float*)d_out;

  float* W = (float*)d_ws;
  float* pooled = W;                         // 0     .. 8191
  float* Stp    = W + 8192;                  // 8192  .. 24575 (4 x 4096 partials)
  float* C      = W + 24576;                 // 24576 .. 28671
  float* Aj     = W + 28672;                 // 28672 .. 28927
  float* CP     = W + 28928;                 // 28928 .. 45311
  unsigned short* Wbf = (unsigned short*)(W + 45312);  // 16384 ushorts

  // zero C only (St is single-writer partials now)
  hipMemsetAsync((char*)d_ws + (size_t)24576 * 4, 0, 4096 * 4, stream);

  k1_pool_zstat<<<dim3(1280), dim3(256), 0, stream>>>(x, z, pooled, Stp, C);
  k2_stats     <<<dim3(64),   dim3(256), 0, stream>>>(pooled, W1, b1, gamma, beta, C, Stp, Aj, CP, Wbf);
  final_kernel <<<dim3(NTOT / 128), dim3(256), 0, stream>>>(z, Wbf, Aj, CP, W2, b2, out);
}